// Round 8
// baseline (5704.935 us; speedup 1.0000x reference)
//
#include <hip/hip_runtime.h>
#include <cmath>

namespace {

typedef _Float16 f16;
typedef f16 f16x8 __attribute__((ext_vector_type(8)));
typedef f16 f16x4 __attribute__((ext_vector_type(4)));
typedef float f32x4 __attribute__((ext_vector_type(4)));

constexpr int B  = 4096;
constexpr int H  = 1024;
constexpr int FH = 4 * H;   // 4096
constexpr int NSTEPS = 45;
constexpr float INVS = 1.0f / 2048.0f;

__device__ __forceinline__ float sigf(float x) { return 1.0f / (1.0f + expf(-x)); }

struct HL { f16 h, l; };
// safe split: hi is 0 or a normal f16; lo = f16((a-hi)*2048) (normal or negligible)
__device__ __forceinline__ HL split16(float a) {
  float ah = (float)(f16)a;
  if (fabsf(a) < 6.1035156e-5f) ah = 0.0f;   // would-be-subnormal hi -> push all into lo
  HL r; r.h = (f16)ah; r.l = (f16)((a - ah) * 2048.0f); return r;
}

__device__ __forceinline__ void async16(f16* lds_dst, const f16* gsrc) {
  __builtin_amdgcn_global_load_lds(
      (const __attribute__((address_space(1))) void*)gsrc,
      (__attribute__((address_space(3))) void*)lds_dst, 16, 0, 0);
}

// ---------------- one-time: pack W_hh (hi/lo split) into MFMA-fragment order ------
// packed elem addr = jb*262144 + kt*8192 + wn*4096 + nf*1024 + hl*512 + lane*8
// content: W_hl[row = nf*1024 + jb*32 + wn*16 + (lane&15)][k = kt*32 + (lane>>4)*8 + 0..7]
__global__ void packW_kernel(const float* __restrict__ W, f16* __restrict__ packed) {
  int tid  = blockIdx.x * 256 + threadIdx.x;      // 0 .. 1048575
  int lane = tid & 63;
  int rest = tid >> 6;
  int hl = rest & 1;
  int nf = (rest >> 1) & 3;
  int wn = (rest >> 3) & 1;
  int kt = (rest >> 4) & 31;
  int jb = rest >> 9;
  int row = nf * 1024 + jb * 32 + wn * 16 + (lane & 15);
  int kk  = kt * 32 + (lane >> 4) * 8;
  const float* src = W + (size_t)row * H + kk;
  f16x8 v;
  #pragma unroll
  for (int i = 0; i < 8; ++i) {
    HL s = split16(src[i]);
    v[i] = hl ? s.l : s.h;
  }
  *(f16x8*)(packed + (size_t)tid * 8) = v;
}

// ---------------- one-time precompute of x-path tables (wave-parallel) ----------------
__global__ void precompute_kernel(
    const float* __restrict__ W_ih, const float* __restrict__ b_ih, const float* __restrict__ b_hh,
    const float* __restrict__ depth_emb, const float* __restrict__ ratio_emb, const float* __restrict__ ks_emb,
    const float* __restrict__ cond_emb, const float* __restrict__ sc_emb, const int* __restrict__ sid_p,
    float* __restrict__ tblD, float* __restrict__ tblR, float* __restrict__ tblK,
    float* __restrict__ condp, float* __restrict__ base0) {
  const int w4   = threadIdx.x >> 6;
  const int lane = threadIdx.x & 63;
  const int j    = blockIdx.x * 4 + w4;
  const float* wr = W_ih + (size_t)j * H;
  const int k = lane * 16;
  float4 wv0 = *(const float4*)(wr + k);
  float4 wv1 = *(const float4*)(wr + k + 4);
  float4 wv2 = *(const float4*)(wr + k + 8);
  float4 wv3 = *(const float4*)(wr + k + 12);

  auto dot = [&](const float* e) -> float {
    float4 e0 = *(const float4*)(e);
    float4 e1 = *(const float4*)(e + 4);
    float4 e2 = *(const float4*)(e + 8);
    float4 e3 = *(const float4*)(e + 12);
    return e0.x*wv0.x + e0.y*wv0.y + e0.z*wv0.z + e0.w*wv0.w
         + e1.x*wv1.x + e1.y*wv1.y + e1.z*wv1.z + e1.w*wv1.w
         + e2.x*wv2.x + e2.y*wv2.y + e2.z*wv2.z + e2.w*wv2.w
         + e3.x*wv3.x + e3.y*wv3.y + e3.z*wv3.z + e3.w*wv3.w;
  };

  float a[15];
  a[0] = dot(depth_emb + k);       a[1] = dot(depth_emb + H + k);   a[2] = dot(depth_emb + 2*H + k);
  a[3] = dot(ratio_emb + k);       a[4] = dot(ratio_emb + H + k);   a[5] = dot(ratio_emb + 2*H + k);
  a[6] = dot(ks_emb + k);          a[7] = dot(ks_emb + H + k);      a[8] = dot(ks_emb + 2*H + k);
  a[9] = a[10] = a[11] = a[12] = a[13] = a[14] = 0.0f;
  constexpr int HH = H / 2;
  int sid = sid_p[0];
  if (lane < 32) {
    a[9]  = dot(cond_emb + 0*HH + k);
    a[10] = dot(cond_emb + 1*HH + k);
    a[11] = dot(cond_emb + 2*HH + k);
    a[12] = dot(cond_emb + 3*HH + k);
    a[13] = dot(cond_emb + 4*HH + k);
  } else {
    a[14] = dot(sc_emb + sid*HH + (k - HH));   // pairs with wr[HH + kk]
  }
  #pragma unroll
  for (int i = 0; i < 15; ++i) {
    #pragma unroll
    for (int off = 32; off > 0; off >>= 1) a[i] += __shfl_xor(a[i], off);
  }
  if (lane == 0) {
    float bias = b_ih[j] + b_hh[j];
    tblD[0*FH+j]=a[0]+bias; tblD[1*FH+j]=a[1]+bias; tblD[2*FH+j]=a[2]+bias;
    tblR[0*FH+j]=a[3]+bias; tblR[1*FH+j]=a[4]+bias; tblR[2*FH+j]=a[5]+bias;
    tblK[0*FH+j]=a[6]+bias; tblK[1*FH+j]=a[7]+bias; tblK[2*FH+j]=a[8]+bias;
    condp[0*FH+j]=a[9]; condp[1*FH+j]=a[10]; condp[2*FH+j]=a[11];
    condp[3*FH+j]=a[12]; condp[4*FH+j]=a[13];
    base0[j] = a[14] + bias;
  }
}

// ---------------- step 0: h=c=0 ----------------
__global__ void step0_kernel(const float* __restrict__ constraints,
                             const float* __restrict__ condp, const float* __restrict__ base0,
                             f16* __restrict__ hhi, f16* __restrict__ hlo, float* __restrict__ c) {
  int idx = blockIdx.x * blockDim.x + threadIdx.x;   // b*H + j
  int b = idx >> 10;
  int j = idx & (H - 1);
  float cv = constraints[b];
  int i0 = 0;
  if (cv >= 12.5f) i0 = 1;
  if (cv >= 15.0f) i0 = 2;
  if (cv >= 17.5f) i0 = 3;
  float right = 10.0f + 2.5f * (float)(i0 + 1);
  float w = (right - cv) / 2.5f;
  const float* c0 = condp + (size_t)i0 * FH;
  const float* c1 = c0 + FH;
  float iw = 1.0f - w;
  float xi = w*c0[j]       + iw*c1[j]       + base0[j];
  float xg = w*c0[2*H+j]   + iw*c1[2*H+j]   + base0[2*H+j];
  float xo = w*c0[3*H+j]   + iw*c1[3*H+j]   + base0[3*H+j];
  float cn = sigf(xi) * tanhf(xg);
  float hn = sigf(xo) * tanhf(cn);
  c[idx] = cn;
  HL s = split16(hn);
  hhi[idx] = s.h; hlo[idx] = s.l;
}

// ---------------- MFMA LSTM step: 256x128 tile, 8 waves ----------------
// A (h) in LDS: 3 buffers x 32KB (AH[0,8192) AL[8192,16384) f16), staged 2 tiles
//   ahead via global_load_lds, chunk-swizzled (phys = kq ^ (R&3) ^ ((R>>2)&3)).
// B (W) streamed packed-global(L2) -> VGPRs. bh prefetched ONE FULL TILE ahead;
//   bl loaded at tile top, consumed only after the 16-MFMA accH cluster.
// No manual waitcnt in the loop: compiler-counted vmcnt waits are (12) before
// accH and (8) before accL -> 8-12 loads stay in flight across every barrier,
// and the vmcnt(12) drain of last tile's stage-loads proves all waves' A-stage
// for tile kt landed before the barrier that opened tile kt (no cross-wave race).
constexpr int ABUF = 16384;   // f16 elems per A buffer (32 KB)

__global__ __launch_bounds__(512, 2) void lstm_step_mfma(
    const f16* __restrict__ hhi, const f16* __restrict__ hlo,
    f16* __restrict__ nhhi, f16* __restrict__ nhlo,
    float* __restrict__ cbuf,
    const f16* __restrict__ packW,
    const float* __restrict__ tbl, const int* __restrict__ sel) {
  __shared__ __align__(16) f16 lds[3 * ABUF];   // 96 KB

  const int tid  = threadIdx.x;
  const int lane = tid & 63;
  const int w    = tid >> 6;
  const int wm   = w >> 1, wn = w & 1;
  const int l15  = lane & 15;
  const int kq   = lane >> 4;

  // XCD-clustered tile assignment (per-XCD W slice stays in its private L2)
  const int L   = blockIdx.x;          // 0..511
  const int xcd = L & 7, seq = L >> 3;
  const int jb  = (xcd << 2) + (seq & 3);
  const int bb  = seq >> 2;
  const int b0  = bb << 8;
  const int j0  = jb << 5;

  f32x4 accH[4][4] = {};
  f32x4 accL[4][4] = {};

  // ---- loop-invariant A fragment offsets (f16 elems) ----
  int offA[4];
  #pragma unroll
  for (int mf = 0; mf < 4; ++mf) {
    int R = wm * 64 + mf * 16 + l15;
    int c = kq ^ (R & 3) ^ ((R >> 2) & 3);
    offA[mf] = R * 32 + c * 8;
  }

  // ---- loop-invariant A staging addresses (4 async16/wave/tile) ----
  const int rs = tid >> 2, cs = tid & 3;
  const int r1 = 128 + rs;
  const int cl0 = cs ^ (rs & 3) ^ ((rs >> 2) & 3);
  const int cl1 = cs ^ (r1 & 3) ^ ((r1 >> 2) & 3);
  const f16* sA0h = hhi + (size_t)(b0 + rs) * H + cl0 * 8;
  const f16* sA0l = hlo + (size_t)(b0 + rs) * H + cl0 * 8;
  const f16* sA1h = hhi + (size_t)(b0 + r1) * H + cl1 * 8;
  const f16* sA1l = hlo + (size_t)(b0 + r1) * H + cl1 * 8;
  const int dA0 = w * 512, dA1 = 4096 + w * 512;

  f16 *bA = lds, *bB = lds + ABUF, *bC = lds + 2 * ABUF;

  auto stageA = [&](f16* buf, int ko) {
    async16(buf + dA0,        sA0h + ko);
    async16(buf + dA0 + 8192, sA0l + ko);
    async16(buf + dA1,        sA1h + ko);
    async16(buf + dA1 + 8192, sA1l + ko);
  };

  // ---- B fragment base (packed layout; see packW_kernel) ----
  const f16* wb = packW + (size_t)jb * 262144 + wn * 4096 + lane * 8;
  // tile kt: bh[nf] at wb + kt*8192 + nf*1024 ; bl[nf] at +512

  f16x8 bh0[4], bh1[4], bl[4];

  // prologue: stage A tiles 0,1; prefetch bh(0)
  stageA(bA, 0);
  stageA(bB, 32);
  #pragma unroll
  for (int nf = 0; nf < 4; ++nf) bh0[nf] = *(const f16x8*)(wb + nf * 1024);
  asm volatile("s_waitcnt vmcnt(8)" ::: "memory");   // own A(0) landed
  __builtin_amdgcn_s_barrier();

  auto tile = [&](int kt, f16x8 (&bhC)[4], f16x8 (&bhN)[4]) {
    const f16* wt = wb + (size_t)kt * 8192;
    // 1) bl(kt): covered by the accH cluster below
    #pragma unroll
    for (int nf = 0; nf < 4; ++nf) bl[nf] = *(const f16x8*)(wt + nf * 1024 + 512);
    // 2) A-stage for tile kt+2 (landed by tile kt+1's accH vmcnt drain)
    if (kt < 30) stageA(bC, (kt + 2) * 32);
    // 3) bh(kt+1): full-tile prefetch distance
    if (kt < 31) {
      #pragma unroll
      for (int nf = 0; nf < 4; ++nf) bhN[nf] = *(const f16x8*)(wt + 8192 + nf * 1024);
    }
    // 4) A fragments from LDS
    f16x8 ah[4], al[4];
    #pragma unroll
    for (int mf = 0; mf < 4; ++mf) {
      ah[mf] = *(const f16x8*)(bA + offA[mf]);
      al[mf] = *(const f16x8*)(bA + offA[mf] + 8192);
    }
    // 5) accH cluster (bh prefetched last tile -> no fresh-load wait)
    #pragma unroll
    for (int mf = 0; mf < 4; ++mf)
      #pragma unroll
      for (int nf = 0; nf < 4; ++nf)
        accH[mf][nf] = __builtin_amdgcn_mfma_f32_16x16x32_f16(ah[mf], bhC[nf], accH[mf][nf], 0, 0, 0);
    // 6) accL clusters (bl landed during accH; compiler waits vmcnt(8))
    #pragma unroll
    for (int mf = 0; mf < 4; ++mf)
      #pragma unroll
      for (int nf = 0; nf < 4; ++nf) {
        accL[mf][nf] = __builtin_amdgcn_mfma_f32_16x16x32_f16(ah[mf], bl[nf], accL[mf][nf], 0, 0, 0);
        accL[mf][nf] = __builtin_amdgcn_mfma_f32_16x16x32_f16(al[mf], bhC[nf], accL[mf][nf], 0, 0, 0);
      }
    __builtin_amdgcn_s_barrier();
    f16* tt = bA; bA = bB; bB = bC; bC = tt;
  };

  for (int kt = 0; kt < 32; kt += 2) {
    tile(kt,     bh0, bh1);
    tile(kt + 1, bh1, bh0);
  }

  // epilogue: gates -> LSTM cell -> c, h(hi/lo)
  const int j = j0 + wn * 16 + l15;
  #pragma unroll
  for (int mf = 0; mf < 4; ++mf) {
    #pragma unroll
    for (int r = 0; r < 4; ++r) {
      int b = b0 + wm * 64 + mf * 16 + kq * 4 + r;
      int s = sel[b];
      const float* tb = tbl + (size_t)s * FH + j;
      float gi = accH[mf][0][r] + accL[mf][0][r] * INVS + tb[0];
      float gf = accH[mf][1][r] + accL[mf][1][r] * INVS + tb[H];
      float gg = accH[mf][2][r] + accL[mf][2][r] * INVS + tb[2*H];
      float go = accH[mf][3][r] + accL[mf][3][r] * INVS + tb[3*H];
      size_t off = (size_t)b * H + j;
      float cp = cbuf[off];
      float cn = sigf(gf) * cp + sigf(gi) * tanhf(gg);
      float hn = sigf(go) * tanhf(cn);
      cbuf[off] = cn;
      HL sp = split16(hn);
      nhhi[off] = sp.h;
      nhlo[off] = sp.l;
    }
  }
}

// ---------------- sampler ----------------
__global__ void sampler_kernel(const f16* __restrict__ hhi, const f16* __restrict__ hlo,
                               const float* __restrict__ selW, const float* __restrict__ selb,
                               const float* __restrict__ gu,
                               float* __restrict__ val_out, float* __restrict__ wb_out,
                               float* __restrict__ p_out,
                               float v0, float v1, float v2,
                               int* __restrict__ sel) {
  int wave = threadIdx.x >> 6;
  int lane = threadIdx.x & 63;
  int b = blockIdx.x * 4 + wave;
  const f16* hh = hhi + (size_t)b * H;
  const f16* hl = hlo + (size_t)b * H;
  float acc0 = 0, acc1 = 0, acc2 = 0;
  #pragma unroll
  for (int ch = 0; ch < 4; ++ch) {
    int k = ch * 256 + lane * 4;
    f16x4 vh = *(const f16x4*)(hh + k);
    f16x4 vl = *(const f16x4*)(hl + k);
    float x0 = (float)vh[0] + (float)vl[0] * INVS;
    float x1 = (float)vh[1] + (float)vl[1] * INVS;
    float x2 = (float)vh[2] + (float)vl[2] * INVS;
    float x3 = (float)vh[3] + (float)vl[3] * INVS;
    float4 w0 = *(const float4*)(selW + k);
    float4 w1 = *(const float4*)(selW + H + k);
    float4 w2 = *(const float4*)(selW + 2*H + k);
    acc0 += x0*w0.x + x1*w0.y + x2*w0.z + x3*w0.w;
    acc1 += x0*w1.x + x1*w1.y + x2*w1.z + x3*w1.w;
    acc2 += x0*w2.x + x1*w2.y + x2*w2.z + x3*w2.w;
  }
  #pragma unroll
  for (int off = 32; off > 0; off >>= 1) {
    acc0 += __shfl_xor(acc0, off);
    acc1 += __shfl_xor(acc1, off);
    acc2 += __shfl_xor(acc2, off);
  }
  if (lane == 0) {
    float y0 = acc0 + selb[0] - logf(-logf(gu[(size_t)b*3 + 0]));
    float y1 = acc1 + selb[1] - logf(-logf(gu[(size_t)b*3 + 1]));
    float y2 = acc2 + selb[2] - logf(-logf(gu[(size_t)b*3 + 2]));
    int s = 0;
    float best = y0;
    if (y1 > best) { s = 1; best = y1; }
    if (y2 > best) { s = 2; best = y2; }
    float e0 = expf(y0 - best), e1 = expf(y1 - best), e2 = expf(y2 - best);
    float inv = 1.0f / (e0 + e1 + e2);
    float p0 = e0 * inv, p1 = e1 * inv, p2 = e2 * inv;
    val_out[b] = (s == 0) ? v0 : ((s == 1) ? v1 : v2);
    wb_out[(size_t)b*3 + 0] = (s == 0) ? 1.0f : 0.0f;
    wb_out[(size_t)b*3 + 1] = (s == 1) ? 1.0f : 0.0f;
    wb_out[(size_t)b*3 + 2] = (s == 2) ? 1.0f : 0.0f;
    p_out[(size_t)b*3 + 0] = p0;
    p_out[(size_t)b*3 + 1] = p1;
    p_out[(size_t)b*3 + 2] = p2;
    sel[b] = s;
  }
}

}  // namespace

extern "C" void kernel_launch(void* const* d_in, const int* in_sizes, int n_in,
                              void* d_out, int out_size, void* d_ws, size_t ws_size,
                              hipStream_t stream) {
  (void)in_sizes; (void)n_in; (void)out_size; (void)ws_size;
  const float* constraints = (const float*)d_in[0];
  const int*   sid         = (const int*)d_in[1];
  const float* gumbel      = (const float*)d_in[2];
  const float* cond_emb    = (const float*)d_in[3];
  const float* sc_emb      = (const float*)d_in[4];
  const float* depth_emb   = (const float*)d_in[5];
  const float* ratio_emb   = (const float*)d_in[6];
  const float* ks_emb      = (const float*)d_in[7];
  const float* W_ih        = (const float*)d_in[8];
  const float* b_ih        = (const float*)d_in[9];
  const float* W_hh        = (const float*)d_in[10];
  const float* b_hh        = (const float*)d_in[11];
  const float* depth_W     = (const float*)d_in[12];
  const float* depth_b     = (const float*)d_in[13];
  const float* width_W     = (const float*)d_in[14];
  const float* width_b     = (const float*)d_in[15];
  const float* ks_W        = (const float*)d_in[16];
  const float* ks_b        = (const float*)d_in[17];

  float* out = (float*)d_out;
  float* ws  = (float*)d_ws;

  float* cb    = ws;                                 // B*H f32 (16MB)
  f16*   packW = (f16*)(cb + (size_t)B * H);         // 8M f16 (16MB), fragment-packed W
  f16*   hhiA  = packW + (size_t)8 * 1024 * 1024;    // B*H f16
  f16*   hloA  = hhiA + (size_t)B * H;
  f16*   hhiB  = hloA + (size_t)B * H;
  f16*   hloB  = hhiB + (size_t)B * H;
  float* tblD  = (float*)(hloB + (size_t)B * H);     // 3*FH f32
  float* tblR  = tblD + 3 * FH;
  float* tblK  = tblR + 3 * FH;
  float* condp = tblK + 3 * FH;                      // 5*FH
  float* base0 = condp + 5 * FH;                     // FH
  int*   sel   = (int*)(base0 + FH);                 // B

  packW_kernel<<<4096, 256, 0, stream>>>(W_hh, packW);
  precompute_kernel<<<FH / 4, 256, 0, stream>>>(
      W_ih, b_ih, b_hh, depth_emb, ratio_emb, ks_emb, cond_emb, sc_emb, sid,
      tblD, tblR, tblK, condp, base0);
  step0_kernel<<<(B * H) / 256, 256, 0, stream>>>(constraints, condp, base0, hhiA, hloA, cb);

  const float* selW_arr[3] = {depth_W, width_W, ks_W};
  const float* selb_arr[3] = {depth_b, width_b, ks_b};
  const float vals[3][3]   = {{2.f,3.f,4.f},{3.f,4.f,6.f},{3.f,5.f,7.f}};
  float* tbl_arr[3]        = {tblD, tblR, tblK};

  const size_t DEPTHS = 0,            RATIOS = (size_t)5*B,   KSS    = (size_t)25*B,
               DWBS   = (size_t)45*B, DPROBS = (size_t)60*B,
               RWBS   = (size_t)75*B, RPROBS = (size_t)135*B,
               KWBS   = (size_t)195*B, KPROBS = (size_t)255*B;

  f16* hhi_cur = hhiA; f16* hlo_cur = hloA;
  f16* hhi_nxt = hhiB; f16* hlo_nxt = hloB;
  for (int t = 0; t < NSTEPS; ++t) {
    if (t > 0) {
      int pt = (t - 1) % 9;
      int ptype = (pt == 0) ? 0 : ((pt & 1) ? 1 : 2);
      lstm_step_mfma<<<512, 512, 0, stream>>>(
          hhi_cur, hlo_cur, hhi_nxt, hlo_nxt, cb, packW, tbl_arr[ptype], sel);
      f16* th = hhi_cur; hhi_cur = hhi_nxt; hhi_nxt = th;
      f16* tl = hlo_cur; hlo_cur = hlo_nxt; hlo_nxt = tl;
    }
    int r = t % 9, u = t / 9;
    int ty, row;
    float *valp, *wbp, *pp;
    if (r == 0)      { ty = 0; row = u;
      valp = out + DEPTHS + (size_t)row*B; wbp = out + DWBS + (size_t)row*B*3; pp = out + DPROBS + (size_t)row*B*3; }
    else if (r & 1)  { ty = 1; row = u*4 + (r-1)/2;
      valp = out + RATIOS + (size_t)row*B; wbp = out + RWBS + (size_t)row*B*3; pp = out + RPROBS + (size_t)row*B*3; }
    else             { ty = 2; row = u*4 + (r-2)/2;
      valp = out + KSS + (size_t)row*B;    wbp = out + KWBS + (size_t)row*B*3; pp = out + KPROBS + (size_t)row*B*3; }
    sampler_kernel<<<B / 4, 256, 0, stream>>>(
        hhi_cur, hlo_cur, selW_arr[ty], selb_arr[ty], gumbel + (size_t)t * B * 3,
        valp, wbp, pp, vals[ty][0], vals[ty][1], vals[ty][2], sel);
  }
}

// Round 9
// 5366.785 us; speedup vs baseline: 1.0630x; 1.0630x over previous
//
#include <hip/hip_runtime.h>
#include <cmath>

namespace {

typedef _Float16 f16;
typedef f16 f16x8 __attribute__((ext_vector_type(8)));
typedef f16 f16x4 __attribute__((ext_vector_type(4)));
typedef float f32x4 __attribute__((ext_vector_type(4)));

constexpr int B  = 4096;
constexpr int H  = 1024;
constexpr int FH = 4 * H;   // 4096
constexpr int NSTEPS = 45;
constexpr float INVS = 1.0f / 2048.0f;

__device__ __forceinline__ float sigf(float x) { return 1.0f / (1.0f + expf(-x)); }

struct HL { f16 h, l; };
// safe split: hi is 0 or a normal f16; lo = f16((a-hi)*2048) (normal or negligible)
__device__ __forceinline__ HL split16(float a) {
  float ah = (float)(f16)a;
  if (fabsf(a) < 6.1035156e-5f) ah = 0.0f;   // would-be-subnormal hi -> push all into lo
  HL r; r.h = (f16)ah; r.l = (f16)((a - ah) * 2048.0f); return r;
}

__device__ __forceinline__ void async16(f16* lds_dst, const f16* gsrc) {
  __builtin_amdgcn_global_load_lds(
      (const __attribute__((address_space(1))) void*)gsrc,
      (__attribute__((address_space(3))) void*)lds_dst, 16, 0, 0);
}

// ---------------- one-time: split W_hh into f16 hi/lo ----------------
__global__ void convertW_kernel(const float* __restrict__ W,
                                f16* __restrict__ Whi, f16* __restrict__ Wlo) {
  size_t i = ((size_t)blockIdx.x * 256 + threadIdx.x) * 4;
  float4 v = *(const float4*)(W + i);
  HL a = split16(v.x), b = split16(v.y), c = split16(v.z), d = split16(v.w);
  f16x4 hi = {a.h, b.h, c.h, d.h};
  f16x4 lo = {a.l, b.l, c.l, d.l};
  *(f16x4*)(Whi + i) = hi;
  *(f16x4*)(Wlo + i) = lo;
}

// ---------------- one-time precompute of x-path tables (wave-parallel) ----------------
__global__ void precompute_kernel(
    const float* __restrict__ W_ih, const float* __restrict__ b_ih, const float* __restrict__ b_hh,
    const float* __restrict__ depth_emb, const float* __restrict__ ratio_emb, const float* __restrict__ ks_emb,
    const float* __restrict__ cond_emb, const float* __restrict__ sc_emb, const int* __restrict__ sid_p,
    float* __restrict__ tblD, float* __restrict__ tblR, float* __restrict__ tblK,
    float* __restrict__ condp, float* __restrict__ base0) {
  const int w4   = threadIdx.x >> 6;
  const int lane = threadIdx.x & 63;
  const int j    = blockIdx.x * 4 + w4;
  const float* wr = W_ih + (size_t)j * H;
  const int k = lane * 16;
  float4 wv0 = *(const float4*)(wr + k);
  float4 wv1 = *(const float4*)(wr + k + 4);
  float4 wv2 = *(const float4*)(wr + k + 8);
  float4 wv3 = *(const float4*)(wr + k + 12);

  auto dot = [&](const float* e) -> float {
    float4 e0 = *(const float4*)(e);
    float4 e1 = *(const float4*)(e + 4);
    float4 e2 = *(const float4*)(e + 8);
    float4 e3 = *(const float4*)(e + 12);
    return e0.x*wv0.x + e0.y*wv0.y + e0.z*wv0.z + e0.w*wv0.w
         + e1.x*wv1.x + e1.y*wv1.y + e1.z*wv1.z + e1.w*wv1.w
         + e2.x*wv2.x + e2.y*wv2.y + e2.z*wv2.z + e2.w*wv2.w
         + e3.x*wv3.x + e3.y*wv3.y + e3.z*wv3.z + e3.w*wv3.w;
  };

  float a[15];
  a[0] = dot(depth_emb + k);       a[1] = dot(depth_emb + H + k);   a[2] = dot(depth_emb + 2*H + k);
  a[3] = dot(ratio_emb + k);       a[4] = dot(ratio_emb + H + k);   a[5] = dot(ratio_emb + 2*H + k);
  a[6] = dot(ks_emb + k);          a[7] = dot(ks_emb + H + k);      a[8] = dot(ks_emb + 2*H + k);
  a[9] = a[10] = a[11] = a[12] = a[13] = a[14] = 0.0f;
  constexpr int HH = H / 2;
  int sid = sid_p[0];
  if (lane < 32) {
    a[9]  = dot(cond_emb + 0*HH + k);
    a[10] = dot(cond_emb + 1*HH + k);
    a[11] = dot(cond_emb + 2*HH + k);
    a[12] = dot(cond_emb + 3*HH + k);
    a[13] = dot(cond_emb + 4*HH + k);
  } else {
    a[14] = dot(sc_emb + sid*HH + (k - HH));   // pairs with wr[HH + kk]
  }
  #pragma unroll
  for (int i = 0; i < 15; ++i) {
    #pragma unroll
    for (int off = 32; off > 0; off >>= 1) a[i] += __shfl_xor(a[i], off);
  }
  if (lane == 0) {
    float bias = b_ih[j] + b_hh[j];
    tblD[0*FH+j]=a[0]+bias; tblD[1*FH+j]=a[1]+bias; tblD[2*FH+j]=a[2]+bias;
    tblR[0*FH+j]=a[3]+bias; tblR[1*FH+j]=a[4]+bias; tblR[2*FH+j]=a[5]+bias;
    tblK[0*FH+j]=a[6]+bias; tblK[1*FH+j]=a[7]+bias; tblK[2*FH+j]=a[8]+bias;
    condp[0*FH+j]=a[9]; condp[1*FH+j]=a[10]; condp[2*FH+j]=a[11];
    condp[3*FH+j]=a[12]; condp[4*FH+j]=a[13];
    base0[j] = a[14] + bias;
  }
}

// ---------------- step 0: h=c=0 ----------------
__global__ void step0_kernel(const float* __restrict__ constraints,
                             const float* __restrict__ condp, const float* __restrict__ base0,
                             f16* __restrict__ hhi, f16* __restrict__ hlo, float* __restrict__ c) {
  int idx = blockIdx.x * blockDim.x + threadIdx.x;   // b*H + j
  int b = idx >> 10;
  int j = idx & (H - 1);
  float cv = constraints[b];
  int i0 = 0;
  if (cv >= 12.5f) i0 = 1;
  if (cv >= 15.0f) i0 = 2;
  if (cv >= 17.5f) i0 = 3;
  float right = 10.0f + 2.5f * (float)(i0 + 1);
  float w = (right - cv) / 2.5f;
  const float* c0 = condp + (size_t)i0 * FH;
  const float* c1 = c0 + FH;
  float iw = 1.0f - w;
  float xi = w*c0[j]       + iw*c1[j]       + base0[j];
  float xg = w*c0[2*H+j]   + iw*c1[2*H+j]   + base0[2*H+j];
  float xo = w*c0[3*H+j]   + iw*c1[3*H+j]   + base0[3*H+j];
  float cn = sigf(xi) * tanhf(xg);
  float hn = sigf(xo) * tanhf(cn);
  c[idx] = cn;
  HL s = split16(hn);
  hhi[idx] = s.h; hlo[idx] = s.l;
}

// ---------------- MFMA LSTM step: 256x128 tile, 8 waves, B-frag reg prefetch ----------
// LDS buffer layout (f16 elems): AH[0,8192) AL[8192,16384) BH[16384,20480) BL[20480,24576)
// Rows stored [row][32 k], 16B-chunk swizzle: phys = kq ^ (R&3) ^ ((R>>2)&3).
// Overlap strategy: bh of tile kt+1 is prefetched to REGISTERS during iter kt
// (from buf[(kt+1)%3], already landed), so iter kt's accH cluster starts after
// only 4 ds_reads (ah). The other 12 reads (al, blC, bhN) land under the 48
// MFMAs. vmcnt(0)+barrier per iter: free (stage issued ~1800cy earlier) and
// guarantees cross-wave stage/read ordering (buffer reads always complete >=1
// barrier before that buffer's next write, since their consuming MFMAs do).
constexpr int BUFE = 24576;   // 48 KB per buffer

__global__ __launch_bounds__(512, 2) void lstm_step_mfma(
    const f16* __restrict__ hhi, const f16* __restrict__ hlo,
    f16* __restrict__ nhhi, f16* __restrict__ nhlo,
    float* __restrict__ cbuf,
    const f16* __restrict__ Whi, const f16* __restrict__ Wlo,
    const float* __restrict__ tbl, const int* __restrict__ sel) {
  __shared__ __align__(16) f16 lds[3 * BUFE];   // 144 KB

  const int tid  = threadIdx.x;
  const int lane = tid & 63;
  const int w    = tid >> 6;
  const int wm   = w >> 1, wn = w & 1;
  const int l15  = lane & 15;
  const int kq   = lane >> 4;

  // XCD-clustered tile assignment (per-XCD W slice stays in its private L2)
  const int L   = blockIdx.x;          // 0..511
  const int xcd = L & 7, seq = L >> 3;
  const int jb  = (xcd << 2) + (seq & 3);
  const int bb  = seq >> 2;
  const int b0  = bb << 8;
  const int j0  = jb << 5;

  f32x4 accH[4][4] = {};
  f32x4 accL[4][4] = {};

  // ---- loop-invariant fragment offsets (f16 elems) ----
  int offA[4], offB[4];
  #pragma unroll
  for (int mf = 0; mf < 4; ++mf) {
    int R = wm * 64 + mf * 16 + l15;
    int c = kq ^ (R & 3) ^ ((R >> 2) & 3);
    offA[mf] = R * 32 + c * 8;
  }
  #pragma unroll
  for (int nf = 0; nf < 4; ++nf) {
    int R = nf * 32 + wn * 16 + l15;
    int c = kq ^ (R & 3) ^ ((R >> 2) & 3);
    offB[nf] = 16384 + R * 32 + c * 8;
  }

  // ---- loop-invariant staging addresses ----
  const int rs = tid >> 2, cs = tid & 3;
  const int r1 = 128 + rs;
  const int cl0 = cs ^ (rs & 3) ^ ((rs >> 2) & 3);
  const int cl1 = cs ^ (r1 & 3) ^ ((r1 >> 2) & 3);
  const int wrow = ((rs >> 5) << 10) + j0 + (rs & 31);   // gate-major permuted W row
  const f16* sA0h = hhi + (size_t)(b0 + rs) * H + cl0 * 8;
  const f16* sA0l = hlo + (size_t)(b0 + rs) * H + cl0 * 8;
  const f16* sA1h = hhi + (size_t)(b0 + r1) * H + cl1 * 8;
  const f16* sA1l = hlo + (size_t)(b0 + r1) * H + cl1 * 8;
  const f16* sBh  = Whi + (size_t)wrow * H + cl0 * 8;
  const f16* sBl  = Wlo + (size_t)wrow * H + cl0 * 8;
  const int dA0 = w * 512, dA1 = 4096 + w * 512, dB = 16384 + w * 512;

  auto stage6 = [&](f16* buf, int ko) {
    async16(buf + dA0,        sA0h + ko);
    async16(buf + dA0 + 8192, sA0l + ko);
    async16(buf + dA1,        sA1h + ko);
    async16(buf + dA1 + 8192, sA1l + ko);
    async16(buf + dB,         sBh + ko);
    async16(buf + dB + 4096,  sBl + ko);
  };

  f16 *bA = lds, *bB = lds + BUFE, *bC = lds + 2 * BUFE;

  f16x8 bhX[4], bhY[4];

  // prologue: stage tiles 0,1; drain; read tile 0's bh into regs
  stage6(bA, 0);
  stage6(bB, 32);
  asm volatile("s_waitcnt vmcnt(0)" ::: "memory");
  __builtin_amdgcn_s_barrier();
  #pragma unroll
  for (int nf = 0; nf < 4; ++nf) bhX[nf] = *(const f16x8*)(bA + offB[nf]);

  // one iteration: consume bhC (current tile's bh, prefetched), prefetch bhN.
  auto tile = [&](int kt, f16x8 (&bhC)[4], f16x8 (&bhN)[4]) {
    if (kt < 30) stage6(bC, (kt + 2) * 32);

    f16x8 ah[4], al[4], bl[4];
    #pragma unroll
    for (int mf = 0; mf < 4; ++mf) ah[mf] = *(const f16x8*)(bA + offA[mf]);
    #pragma unroll
    for (int mf = 0; mf < 4; ++mf) al[mf] = *(const f16x8*)(bA + offA[mf] + 8192);
    #pragma unroll
    for (int nf = 0; nf < 4; ++nf) bl[nf] = *(const f16x8*)(bA + offB[nf] + 4096);
    if (kt < 31) {
      #pragma unroll
      for (int nf = 0; nf < 4; ++nf) bhN[nf] = *(const f16x8*)(bB + offB[nf]);
    }

    // accH first: needs only ah (first 4 reads) + bhC (already in regs)
    #pragma unroll
    for (int mf = 0; mf < 4; ++mf)
      #pragma unroll
      for (int nf = 0; nf < 4; ++nf)
        accH[mf][nf] = __builtin_amdgcn_mfma_f32_16x16x32_f16(ah[mf], bhC[nf], accH[mf][nf], 0, 0, 0);
    #pragma unroll
    for (int mf = 0; mf < 4; ++mf)
      #pragma unroll
      for (int nf = 0; nf < 4; ++nf)
        accL[mf][nf] = __builtin_amdgcn_mfma_f32_16x16x32_f16(ah[mf], bl[nf], accL[mf][nf], 0, 0, 0);
    #pragma unroll
    for (int mf = 0; mf < 4; ++mf)
      #pragma unroll
      for (int nf = 0; nf < 4; ++nf)
        accL[mf][nf] = __builtin_amdgcn_mfma_f32_16x16x32_f16(al[mf], bhC[nf], accL[mf][nf], 0, 0, 0);

    asm volatile("s_waitcnt vmcnt(0)" ::: "memory");   // stage landed (issued ~1800cy ago)
    __builtin_amdgcn_s_barrier();
    f16* t = bA; bA = bB; bB = bC; bC = t;
  };

  for (int kt = 0; kt < 32; kt += 2) {
    tile(kt,     bhX, bhY);
    tile(kt + 1, bhY, bhX);
  }

  // epilogue: gates -> LSTM cell -> c, h(hi/lo)
  const int j = j0 + wn * 16 + l15;
  #pragma unroll
  for (int mf = 0; mf < 4; ++mf) {
    #pragma unroll
    for (int r = 0; r < 4; ++r) {
      int b = b0 + wm * 64 + mf * 16 + kq * 4 + r;
      int s = sel[b];
      const float* tb = tbl + (size_t)s * FH + j;
      float gi = accH[mf][0][r] + accL[mf][0][r] * INVS + tb[0];
      float gf = accH[mf][1][r] + accL[mf][1][r] * INVS + tb[H];
      float gg = accH[mf][2][r] + accL[mf][2][r] * INVS + tb[2*H];
      float go = accH[mf][3][r] + accL[mf][3][r] * INVS + tb[3*H];
      size_t off = (size_t)b * H + j;
      float cp = cbuf[off];
      float cn = sigf(gf) * cp + sigf(gi) * tanhf(gg);
      float hn = sigf(go) * tanhf(cn);
      cbuf[off] = cn;
      HL sp = split16(hn);
      nhhi[off] = sp.h;
      nhlo[off] = sp.l;
    }
  }
}

// ---------------- sampler ----------------
__global__ void sampler_kernel(const f16* __restrict__ hhi, const f16* __restrict__ hlo,
                               const float* __restrict__ selW, const float* __restrict__ selb,
                               const float* __restrict__ gu,
                               float* __restrict__ val_out, float* __restrict__ wb_out,
                               float* __restrict__ p_out,
                               float v0, float v1, float v2,
                               int* __restrict__ sel) {
  int wave = threadIdx.x >> 6;
  int lane = threadIdx.x & 63;
  int b = blockIdx.x * 4 + wave;
  const f16* hh = hhi + (size_t)b * H;
  const f16* hl = hlo + (size_t)b * H;
  float acc0 = 0, acc1 = 0, acc2 = 0;
  #pragma unroll
  for (int ch = 0; ch < 4; ++ch) {
    int k = ch * 256 + lane * 4;
    f16x4 vh = *(const f16x4*)(hh + k);
    f16x4 vl = *(const f16x4*)(hl + k);
    float x0 = (float)vh[0] + (float)vl[0] * INVS;
    float x1 = (float)vh[1] + (float)vl[1] * INVS;
    float x2 = (float)vh[2] + (float)vl[2] * INVS;
    float x3 = (float)vh[3] + (float)vl[3] * INVS;
    float4 w0 = *(const float4*)(selW + k);
    float4 w1 = *(const float4*)(selW + H + k);
    float4 w2 = *(const float4*)(selW + 2*H + k);
    acc0 += x0*w0.x + x1*w0.y + x2*w0.z + x3*w0.w;
    acc1 += x0*w1.x + x1*w1.y + x2*w1.z + x3*w1.w;
    acc2 += x0*w2.x + x1*w2.y + x2*w2.z + x3*w2.w;
  }
  #pragma unroll
  for (int off = 32; off > 0; off >>= 1) {
    acc0 += __shfl_xor(acc0, off);
    acc1 += __shfl_xor(acc1, off);
    acc2 += __shfl_xor(acc2, off);
  }
  if (lane == 0) {
    float y0 = acc0 + selb[0] - logf(-logf(gu[(size_t)b*3 + 0]));
    float y1 = acc1 + selb[1] - logf(-logf(gu[(size_t)b*3 + 1]));
    float y2 = acc2 + selb[2] - logf(-logf(gu[(size_t)b*3 + 2]));
    int s = 0;
    float best = y0;
    if (y1 > best) { s = 1; best = y1; }
    if (y2 > best) { s = 2; best = y2; }
    float e0 = expf(y0 - best), e1 = expf(y1 - best), e2 = expf(y2 - best);
    float inv = 1.0f / (e0 + e1 + e2);
    float p0 = e0 * inv, p1 = e1 * inv, p2 = e2 * inv;
    val_out[b] = (s == 0) ? v0 : ((s == 1) ? v1 : v2);
    wb_out[(size_t)b*3 + 0] = (s == 0) ? 1.0f : 0.0f;
    wb_out[(size_t)b*3 + 1] = (s == 1) ? 1.0f : 0.0f;
    wb_out[(size_t)b*3 + 2] = (s == 2) ? 1.0f : 0.0f;
    p_out[(size_t)b*3 + 0] = p0;
    p_out[(size_t)b*3 + 1] = p1;
    p_out[(size_t)b*3 + 2] = p2;
    sel[b] = s;
  }
}

}  // namespace

extern "C" void kernel_launch(void* const* d_in, const int* in_sizes, int n_in,
                              void* d_out, int out_size, void* d_ws, size_t ws_size,
                              hipStream_t stream) {
  (void)in_sizes; (void)n_in; (void)out_size; (void)ws_size;
  const float* constraints = (const float*)d_in[0];
  const int*   sid         = (const int*)d_in[1];
  const float* gumbel      = (const float*)d_in[2];
  const float* cond_emb    = (const float*)d_in[3];
  const float* sc_emb      = (const float*)d_in[4];
  const float* depth_emb   = (const float*)d_in[5];
  const float* ratio_emb   = (const float*)d_in[6];
  const float* ks_emb      = (const float*)d_in[7];
  const float* W_ih        = (const float*)d_in[8];
  const float* b_ih        = (const float*)d_in[9];
  const float* W_hh        = (const float*)d_in[10];
  const float* b_hh        = (const float*)d_in[11];
  const float* depth_W     = (const float*)d_in[12];
  const float* depth_b     = (const float*)d_in[13];
  const float* width_W     = (const float*)d_in[14];
  const float* width_b     = (const float*)d_in[15];
  const float* ks_W        = (const float*)d_in[16];
  const float* ks_b        = (const float*)d_in[17];

  float* out = (float*)d_out;
  float* ws  = (float*)d_ws;

  float* cb    = ws;                                 // B*H f32 (16MB)
  f16*   W16hi = (f16*)(cb + (size_t)B * H);         // FH*H f16 (8MB)
  f16*   W16lo = W16hi + (size_t)FH * H;             // 8MB
  f16*   hhiA  = W16lo + (size_t)FH * H;             // B*H f16
  f16*   hloA  = hhiA + (size_t)B * H;
  f16*   hhiB  = hloA + (size_t)B * H;
  f16*   hloB  = hhiB + (size_t)B * H;
  float* tblD  = (float*)(hloB + (size_t)B * H);     // 3*FH f32
  float* tblR  = tblD + 3 * FH;
  float* tblK  = tblR + 3 * FH;
  float* condp = tblK + 3 * FH;                      // 5*FH
  float* base0 = condp + 5 * FH;                     // FH
  int*   sel   = (int*)(base0 + FH);                 // B

  convertW_kernel<<<(FH * H / 4) / 256, 256, 0, stream>>>(W_hh, W16hi, W16lo);
  precompute_kernel<<<FH / 4, 256, 0, stream>>>(
      W_ih, b_ih, b_hh, depth_emb, ratio_emb, ks_emb, cond_emb, sc_emb, sid,
      tblD, tblR, tblK, condp, base0);
  step0_kernel<<<(B * H) / 256, 256, 0, stream>>>(constraints, condp, base0, hhiA, hloA, cb);

  const float* selW_arr[3] = {depth_W, width_W, ks_W};
  const float* selb_arr[3] = {depth_b, width_b, ks_b};
  const float vals[3][3]   = {{2.f,3.f,4.f},{3.f,4.f,6.f},{3.f,5.f,7.f}};
  float* tbl_arr[3]        = {tblD, tblR, tblK};

  const size_t DEPTHS = 0,            RATIOS = (size_t)5*B,   KSS    = (size_t)25*B,
               DWBS   = (size_t)45*B, DPROBS = (size_t)60*B,
               RWBS   = (size_t)75*B, RPROBS = (size_t)135*B,
               KWBS   = (size_t)195*B, KPROBS = (size_t)255*B;

  f16* hhi_cur = hhiA; f16* hlo_cur = hloA;
  f16* hhi_nxt = hhiB; f16* hlo_nxt = hloB;
  for (int t = 0; t < NSTEPS; ++t) {
    if (t > 0) {
      int pt = (t - 1) % 9;
      int ptype = (pt == 0) ? 0 : ((pt & 1) ? 1 : 2);
      lstm_step_mfma<<<512, 512, 0, stream>>>(
          hhi_cur, hlo_cur, hhi_nxt, hlo_nxt, cb, W16hi, W16lo, tbl_arr[ptype], sel);
      f16* th = hhi_cur; hhi_cur = hhi_nxt; hhi_nxt = th;
      f16* tl = hlo_cur; hlo_cur = hlo_nxt; hlo_nxt = tl;
    }
    int r = t % 9, u = t / 9;
    int ty, row;
    float *valp, *wbp, *pp;
    if (r == 0)      { ty = 0; row = u;
      valp = out + DEPTHS + (size_t)row*B; wbp = out + DWBS + (size_t)row*B*3; pp = out + DPROBS + (size_t)row*B*3; }
    else if (r & 1)  { ty = 1; row = u*4 + (r-1)/2;
      valp = out + RATIOS + (size_t)row*B; wbp = out + RWBS + (size_t)row*B*3; pp = out + RPROBS + (size_t)row*B*3; }
    else             { ty = 2; row = u*4 + (r-2)/2;
      valp = out + KSS + (size_t)row*B;    wbp = out + KWBS + (size_t)row*B*3; pp = out + KPROBS + (size_t)row*B*3; }
    sampler_kernel<<<B / 4, 256, 0, stream>>>(
        hhi_cur, hlo_cur, selW_arr[ty], selb_arr[ty], gumbel + (size_t)t * B * 3,
        valp, wbp, pp, vals[ty][0], vals[ty][1], vals[ty][2], sel);
  }
}